// Round 1
// baseline (1464.716 us; speedup 1.0000x reference)
//
#include <hip/hip_runtime.h>
#include <hip/hip_bf16.h>
#include <cstdint>

// Problem constants (fixed by the reference).
static constexpr int N = 100000;
static constexpr int E = 3200000;
static constexpr float BN_EPS = 1e-5f;

// ---------------- workspace layout ----------------
static constexpr size_t OFF_DEG_OUT = 0;                               // N int
static constexpr size_t OFF_DEG_IN  = OFF_DEG_OUT + (size_t)N * 4;     // N int
static constexpr size_t OFF_SUMS1   = OFF_DEG_IN  + (size_t)N * 4;     // 256 f32 (sum,sumsq)
static constexpr size_t OFF_SUMS2   = OFF_SUMS1 + 256 * 4;             // 256 f32
static constexpr size_t MEMSET_BYTES= OFF_SUMS2 + 256 * 4;             // zeroed region
static constexpr size_t OFF_NORM_S  = 802304;                          // N f32
static constexpr size_t OFF_NORM_D  = OFF_NORM_S + 400000;             // N f32
static constexpr size_t OFF_RP      = OFF_NORM_D + 400000;             // N+1 int
static constexpr size_t OFF_CUR     = OFF_RP + 400128;                 // N int
static constexpr size_t OFF_AB1     = OFF_CUR + 400000;                // 256 f32 (a|c)
static constexpr size_t OFF_AB2     = OFF_AB1 + 1024;                  // 256 f32
static constexpr size_t OFF_COL     = OFF_AB2 + 1024;                  // E int
static constexpr size_t OFF_H       = OFF_COL + (size_t)E * 4;         // N*128 bf16
static constexpr size_t OFF_T       = OFF_H + (size_t)N * 128 * 2;     // N*128 bf16
static constexpr size_t OFF_M       = OFF_T + (size_t)N * 128 * 2;     // N*128 f32

__device__ inline float ldf(const float* p, int i) { return p[i]; }
__device__ inline float ldf(const __hip_bfloat16* p, int i) { return __bfloat162float(p[i]); }
__device__ inline float bflo(unsigned v) { return __uint_as_float(v << 16); }
__device__ inline float bfhi(unsigned v) { return __uint_as_float(v & 0xffff0000u); }

// ---------------- graph preprocessing ----------------
__global__ __launch_bounds__(256) void k_deg(const int* __restrict__ src,
                                             const int* __restrict__ dst,
                                             int* __restrict__ deg_out,
                                             int* __restrict__ deg_in) {
    int e = blockIdx.x * 256 + threadIdx.x;
    if (e < E) {
        atomicAdd(&deg_out[src[e]], 1);
        atomicAdd(&deg_in[dst[e]], 1);
    }
}

__global__ __launch_bounds__(256) void k_norm(const int* __restrict__ deg_out,
                                              const int* __restrict__ deg_in,
                                              float* __restrict__ norm_s,
                                              float* __restrict__ norm_d) {
    int n = blockIdx.x * 256 + threadIdx.x;
    if (n < N) {
        norm_s[n] = rsqrtf(fmaxf((float)deg_out[n], 1.0f));
        norm_d[n] = rsqrtf(fmaxf((float)deg_in[n], 1.0f));
    }
}

// single-block exclusive scan of deg_in -> row_ptr (and cursor copy)
__global__ __launch_bounds__(1024) void k_scan(const int* __restrict__ deg,
                                               int* __restrict__ rp,
                                               int* __restrict__ cur) {
    __shared__ int sd[1024];
    int tid = threadIdx.x;
    int carry = 0;
    for (int base = 0; base < N; base += 1024) {
        int i = base + tid;
        int v = (i < N) ? deg[i] : 0;
        sd[tid] = v;
        __syncthreads();
        for (int off = 1; off < 1024; off <<= 1) {
            int t = (tid >= off) ? sd[tid - off] : 0;
            __syncthreads();
            sd[tid] += t;
            __syncthreads();
        }
        int excl = sd[tid] - v;
        if (i < N) { rp[i] = carry + excl; cur[i] = carry + excl; }
        carry += sd[1023];
        __syncthreads();
    }
    if (tid == 0) rp[N] = carry;
}

__global__ __launch_bounds__(256) void k_bucket(const int* __restrict__ src,
                                                const int* __restrict__ dst,
                                                int* __restrict__ cur,
                                                int* __restrict__ col) {
    int e = blockIdx.x * 256 + threadIdx.x;
    if (e < E) {
        int pos = atomicAdd(&cur[dst[e]], 1);
        col[pos] = src[e];
    }
}

// ---------------- GEMM: t = ((in * a + c) * norm_s) @ W, out bf16 ----------------
// in: N x 128, W: 128 x FOUT (row-major f32), out: N x FOUT bf16
template <typename TIn, int FOUT, bool AFFINE>
__global__ __launch_bounds__(256) void k_gemm(const TIn* __restrict__ in,
                                              const float* __restrict__ W,
                                              const float* __restrict__ rowscale,
                                              const float* __restrict__ ab, // a[0..127], c[128..255]
                                              __hip_bfloat16* __restrict__ out) {
    __shared__ float Ws[64 * FOUT];   // half of K at a time (keep LDS <= 48KB)
    __shared__ float Xs[32][128];
    const int tid = threadIdx.x;
    const int r0 = blockIdx.x * 32;

    // stage 32 input rows, with row scale (and BN affine fold)
    for (int i = tid; i < 32 * 128; i += 256) {
        int rr = i >> 7, k = i & 127;
        int row = r0 + rr;
        float v = 0.0f;
        if (row < N) {
            v = ldf(in, row * 128 + k);
            if (AFFINE) v = v * ab[k] + ab[128 + k];
            v *= rowscale[row];
        }
        Xs[rr][k] = v;
    }

    const int wave = tid >> 6, lane = tid & 63;
    constexpr int NC = FOUT / 64; // 2 for FOUT=128, 1 for FOUT=64
    float acc[8][NC];
#pragma unroll
    for (int rr = 0; rr < 8; ++rr)
#pragma unroll
        for (int cc = 0; cc < NC; ++cc) acc[rr][cc] = 0.0f;

    for (int kb = 0; kb < 128; kb += 64) {
        __syncthreads();  // also covers Xs staging on first iteration; protects Ws reuse
        for (int i = tid; i < 64 * FOUT; i += 256)
            Ws[i] = W[(size_t)(kb + i / FOUT) * FOUT + (i % FOUT)];
        __syncthreads();
#pragma unroll 4
        for (int k = 0; k < 64; ++k) {
            float w0 = Ws[k * FOUT + lane];
            float w1 = (NC == 2) ? Ws[k * FOUT + 64 + lane] : 0.0f;
#pragma unroll
            for (int rr = 0; rr < 8; ++rr) {
                float xv = Xs[wave * 8 + rr][kb + k];
                acc[rr][0] += xv * w0;
                if (NC == 2) acc[rr][1] += xv * w1;
            }
        }
    }

#pragma unroll
    for (int rr = 0; rr < 8; ++rr) {
        int row = r0 + wave * 8 + rr;
        if (row < N) {
            out[(size_t)row * FOUT + lane] = __float2bfloat16(acc[rr][0]);
            if (NC == 2) out[(size_t)row * FOUT + lane + 64] = __float2bfloat16(acc[rr][1]);
        }
    }
}

// ---------------- CSR gather aggregation ----------------
// FOUT=128: one wave per node, lane handles 2 features via packed uint loads
__global__ __launch_bounds__(256) void k_agg128(const unsigned* __restrict__ T2, // N x 64 uints
                                                const int* __restrict__ rp,
                                                const int* __restrict__ col,
                                                float2* __restrict__ M2) {       // N x 64 float2
    int wave = threadIdx.x >> 6, lane = threadIdx.x & 63;
    int n = blockIdx.x * 4 + wave;
    if (n >= N) return;
    int beg = rp[n], end = rp[n + 1];
    float a0 = 0.0f, a1 = 0.0f;
    int e = beg;
    for (; e + 4 <= end; e += 4) {
        int s0 = col[e], s1 = col[e + 1], s2 = col[e + 2], s3 = col[e + 3];
        unsigned v0 = T2[s0 * 64 + lane];
        unsigned v1 = T2[s1 * 64 + lane];
        unsigned v2 = T2[s2 * 64 + lane];
        unsigned v3 = T2[s3 * 64 + lane];
        a0 += bflo(v0) + bflo(v1) + bflo(v2) + bflo(v3);
        a1 += bfhi(v0) + bfhi(v1) + bfhi(v2) + bfhi(v3);
    }
    for (; e < end; ++e) {
        unsigned v = T2[col[e] * 64 + lane];
        a0 += bflo(v); a1 += bfhi(v);
    }
    M2[n * 64 + lane] = make_float2(a0, a1);
}

// FOUT=64: one wave per node, lane = feature
__global__ __launch_bounds__(256) void k_agg64(const __hip_bfloat16* __restrict__ T,
                                               const int* __restrict__ rp,
                                               const int* __restrict__ col,
                                               float* __restrict__ M) {
    int wave = threadIdx.x >> 6, lane = threadIdx.x & 63;
    int n = blockIdx.x * 4 + wave;
    if (n >= N) return;
    int beg = rp[n], end = rp[n + 1];
    float a0 = 0.0f;
    int e = beg;
    for (; e + 4 <= end; e += 4) {
        int s0 = col[e], s1 = col[e + 1], s2 = col[e + 2], s3 = col[e + 3];
        float v0 = __bfloat162float(T[s0 * 64 + lane]);
        float v1 = __bfloat162float(T[s1 * 64 + lane]);
        float v2 = __bfloat162float(T[s2 * 64 + lane]);
        float v3 = __bfloat162float(T[s3 * 64 + lane]);
        a0 += v0 + v1 + v2 + v3;
    }
    for (; e < end; ++e) a0 += __bfloat162float(T[col[e] * 64 + lane]);
    M[n * 64 + lane] = a0;
}

// ---------------- post: z = m*norm_d + b; r = relu(z); H = r; BN partial sums ----------------
__global__ __launch_bounds__(256) void k_post(const float* __restrict__ M,
                                              const float* __restrict__ norm_d,
                                              const float* __restrict__ bias,
                                              __hip_bfloat16* __restrict__ H,
                                              float* __restrict__ sums) { // [0..127]=sum, [128..255]=sumsq
    int tid = threadIdx.x;
    int f = tid & 127;
    float b = bias[f];
    float s = 0.0f, sq = 0.0f;
    const int total = N * 128;
    const int stride = gridDim.x * 256;
    for (int idx = blockIdx.x * 256 + tid; idx < total; idx += stride) {
        int row = idx >> 7;
        float z = M[idx] * norm_d[row] + b;
        float r = fmaxf(z, 0.0f);
        H[idx] = __float2bfloat16(r);
        s += r; sq += r * r;
    }
    __shared__ float ls[256], lq[256];
    ls[tid] = s; lq[tid] = sq;
    __syncthreads();
    if (tid < 128) {
        atomicAdd(&sums[f], ls[tid] + ls[tid + 128]);
        atomicAdd(&sums[128 + f], lq[tid] + lq[tid + 128]);
    }
}

__global__ __launch_bounds__(128) void k_bnfin(const float* __restrict__ sums,
                                               const float* __restrict__ gamma,
                                               const float* __restrict__ beta,
                                               float* __restrict__ ab) {
    int f = threadIdx.x;
    float mu = sums[f] * (1.0f / N);
    float var = sums[128 + f] * (1.0f / N) - mu * mu;
    float a = gamma[f] * rsqrtf(var + BN_EPS);
    ab[f] = a;
    ab[128 + f] = beta[f] - mu * a;
}

// ---------------- final: z = m*norm_d + b3; log_softmax over 64 feats ----------------
__global__ __launch_bounds__(256) void k_lsm(const float* __restrict__ M,
                                             const float* __restrict__ norm_d,
                                             const float* __restrict__ b3,
                                             float* __restrict__ out) {
    int wave = threadIdx.x >> 6, lane = threadIdx.x & 63;
    int n = blockIdx.x * 4 + wave;
    if (n >= N) return;
    float z = M[n * 64 + lane] * norm_d[n] + b3[lane];
    float m = z;
    for (int off = 32; off; off >>= 1) m = fmaxf(m, __shfl_xor(m, off));
    float e = __expf(z - m);
    float ssum = e;
    for (int off = 32; off; off >>= 1) ssum += __shfl_xor(ssum, off);
    out[n * 64 + lane] = z - m - __logf(ssum);
}

extern "C" void kernel_launch(void* const* d_in, const int* in_sizes, int n_in,
                              void* d_out, int out_size, void* d_ws, size_t ws_size,
                              hipStream_t stream) {
    const float* x  = (const float*)d_in[0];
    const int* src  = (const int*)d_in[1];
    const int* dst  = (const int*)d_in[2];
    const float* W1 = (const float*)d_in[3];
    const float* b1 = (const float*)d_in[4];
    const float* W2 = (const float*)d_in[5];
    const float* b2 = (const float*)d_in[6];
    const float* W3 = (const float*)d_in[7];
    const float* b3 = (const float*)d_in[8];
    const float* g1 = (const float*)d_in[9];
    const float* be1= (const float*)d_in[10];
    const float* g2 = (const float*)d_in[11];
    const float* be2= (const float*)d_in[12];
    float* out = (float*)d_out;

    char* ws = (char*)d_ws;
    int*   deg_out = (int*)(ws + OFF_DEG_OUT);
    int*   deg_in  = (int*)(ws + OFF_DEG_IN);
    float* sums1   = (float*)(ws + OFF_SUMS1);
    float* sums2   = (float*)(ws + OFF_SUMS2);
    float* norm_s  = (float*)(ws + OFF_NORM_S);
    float* norm_d  = (float*)(ws + OFF_NORM_D);
    int*   rp      = (int*)(ws + OFF_RP);
    int*   cur     = (int*)(ws + OFF_CUR);
    float* ab1     = (float*)(ws + OFF_AB1);
    float* ab2     = (float*)(ws + OFF_AB2);
    int*   col     = (int*)(ws + OFF_COL);
    __hip_bfloat16* H = (__hip_bfloat16*)(ws + OFF_H);
    __hip_bfloat16* T = (__hip_bfloat16*)(ws + OFF_T);
    float* M       = (float*)(ws + OFF_M);

    hipMemsetAsync(ws, 0, MEMSET_BYTES, stream);

    k_deg<<<(E + 255) / 256, 256, 0, stream>>>(src, dst, deg_out, deg_in);
    k_norm<<<(N + 255) / 256, 256, 0, stream>>>(deg_out, deg_in, norm_s, norm_d);
    k_scan<<<1, 1024, 0, stream>>>(deg_in, rp, cur);
    k_bucket<<<(E + 255) / 256, 256, 0, stream>>>(src, dst, cur, col);

    const int gemm_grid = (N + 31) / 32;
    const int node_grid = (N + 3) / 4;

    // Layer 1
    k_gemm<float, 128, false><<<gemm_grid, 256, 0, stream>>>(x, W1, norm_s, nullptr, T);
    k_agg128<<<node_grid, 256, 0, stream>>>((const unsigned*)T, rp, col, (float2*)M);
    k_post<<<1024, 256, 0, stream>>>(M, norm_d, b1, H, sums1);
    k_bnfin<<<1, 128, 0, stream>>>(sums1, g1, be1, ab1);

    // Layer 2
    k_gemm<__hip_bfloat16, 128, true><<<gemm_grid, 256, 0, stream>>>(H, W2, norm_s, ab1, T);
    k_agg128<<<node_grid, 256, 0, stream>>>((const unsigned*)T, rp, col, (float2*)M);
    k_post<<<1024, 256, 0, stream>>>(M, norm_d, b2, H, sums2);
    k_bnfin<<<1, 128, 0, stream>>>(sums2, g2, be2, ab2);

    // Layer 3 (64 outputs) + log_softmax
    k_gemm<__hip_bfloat16, 64, true><<<gemm_grid, 256, 0, stream>>>(H, W3, norm_s, ab2, T);
    k_agg64<<<node_grid, 256, 0, stream>>>(T, rp, col, M);
    k_lsm<<<node_grid, 256, 0, stream>>>(M, norm_d, b3, out);
}

// Round 2
// 1222.862 us; speedup vs baseline: 1.1978x; 1.1978x over previous
//
#include <hip/hip_runtime.h>
#include <hip/hip_bf16.h>
#include <cstdint>

// Problem constants (fixed by the reference).
static constexpr int N = 100000;
static constexpr int E = 3200000;
static constexpr float BN_EPS = 1e-5f;

static constexpr int SCAN_B = 1024;                   // scan block size
static constexpr int NB = (N + SCAN_B - 1) / SCAN_B;  // 98 scan blocks
static constexpr int NBUCK = (N + 127) >> 7;          // 782 dst-buckets of 128 nodes

// ---------------- workspace layout ----------------
static constexpr size_t OFF_DEG_OUT = 0;                               // N int
static constexpr size_t OFF_DEG_IN  = OFF_DEG_OUT + (size_t)N * 4;     // N int
static constexpr size_t OFF_SUMS1   = OFF_DEG_IN  + (size_t)N * 4;     // 256 f32 (sum,sumsq)
static constexpr size_t OFF_SUMS2   = OFF_SUMS1 + 256 * 4;             // 256 f32
static constexpr size_t MEMSET_BYTES= OFF_SUMS2 + 256 * 4;             // zeroed region
static constexpr size_t OFF_NORM_S  = 802304;                          // N f32
static constexpr size_t OFF_NORM_D  = OFF_NORM_S + 400000;             // N f32
static constexpr size_t OFF_RP      = OFF_NORM_D + 400000;             // N+1 int
static constexpr size_t OFF_PART    = OFF_RP + 400128;                 // NB int (scan partials)
static constexpr size_t OFF_COARSE  = OFF_PART + 4096;                 // NBUCK*16 int (padded cursors)
static constexpr size_t OFF_AB1     = OFF_COARSE + (size_t)NBUCK * 64; // 256 f32 (a|c)
static constexpr size_t OFF_AB2     = OFF_AB1 + 1024;                  // 256 f32
static constexpr size_t OFF_COL     = OFF_AB2 + 1024;                  // E int
static constexpr size_t OFF_H       = OFF_COL + (size_t)E * 4;         // N*128 bf16
static constexpr size_t OFF_T       = OFF_H + (size_t)N * 128 * 2;     // N*128 bf16
static constexpr size_t OFF_M       = OFF_T + (size_t)N * 128 * 2;     // N*128 f32 (aliased: edge pairs E*8 during CSR build)

__device__ inline float ldf(const float* p, int i) { return p[i]; }
__device__ inline float ldf(const __hip_bfloat16* p, int i) { return __bfloat162float(p[i]); }
__device__ inline float bflo(unsigned v) { return __uint_as_float(v << 16); }
__device__ inline float bfhi(unsigned v) { return __uint_as_float(v & 0xffff0000u); }

// ---------------- graph preprocessing ----------------
__global__ __launch_bounds__(256) void k_deg(const int* __restrict__ src,
                                             const int* __restrict__ dst,
                                             int* __restrict__ deg_out,
                                             int* __restrict__ deg_in) {
    int e = blockIdx.x * 256 + threadIdx.x;
    if (e < E) {
        atomicAdd(&deg_out[src[e]], 1);
        atomicAdd(&deg_in[dst[e]], 1);
    }
}

__global__ __launch_bounds__(256) void k_norm(const int* __restrict__ deg_out,
                                              const int* __restrict__ deg_in,
                                              float* __restrict__ norm_s,
                                              float* __restrict__ norm_d) {
    int n = blockIdx.x * 256 + threadIdx.x;
    if (n < N) {
        norm_s[n] = rsqrtf(fmaxf((float)deg_out[n], 1.0f));
        norm_d[n] = rsqrtf(fmaxf((float)deg_in[n], 1.0f));
    }
}

// ---- hierarchical exclusive scan of deg_in -> rp (and coarse bucket cursors) ----
__global__ __launch_bounds__(SCAN_B) void k_part(const int* __restrict__ deg,
                                                 int* __restrict__ part) {
    __shared__ int sd[SCAN_B];
    int tid = threadIdx.x;
    int i = blockIdx.x * SCAN_B + tid;
    sd[tid] = (i < N) ? deg[i] : 0;
    __syncthreads();
    for (int s = SCAN_B / 2; s; s >>= 1) {
        if (tid < s) sd[tid] += sd[tid + s];
        __syncthreads();
    }
    if (tid == 0) part[blockIdx.x] = sd[0];
}

__global__ __launch_bounds__(128) void k_scanpart(int* __restrict__ part,
                                                  int* __restrict__ rp) {
    __shared__ int sd[128];
    int tid = threadIdx.x;
    int v = (tid < NB) ? part[tid] : 0;
    sd[tid] = v;
    __syncthreads();
    for (int off = 1; off < 128; off <<= 1) {
        int t = (tid >= off) ? sd[tid - off] : 0;
        __syncthreads();
        sd[tid] += t;
        __syncthreads();
    }
    if (tid < NB) part[tid] = sd[tid] - v;   // exclusive block offset
    if (tid == 127) rp[N] = sd[127];         // total == E
}

__global__ __launch_bounds__(SCAN_B) void k_apply(const int* __restrict__ deg,
                                                  const int* __restrict__ part,
                                                  int* __restrict__ rp,
                                                  int* __restrict__ coarse) {
    __shared__ int sd[SCAN_B];
    int tid = threadIdx.x;
    int i = blockIdx.x * SCAN_B + tid;
    int v = (i < N) ? deg[i] : 0;
    sd[tid] = v;
    __syncthreads();
    for (int off = 1; off < SCAN_B; off <<= 1) {
        int t = (tid >= off) ? sd[tid - off] : 0;
        __syncthreads();
        sd[tid] += t;
        __syncthreads();
    }
    int val = part[blockIdx.x] + sd[tid] - v;
    if (i < N) {
        rp[i] = val;
        if ((i & 127) == 0) coarse[(i >> 7) * 16] = val;  // padded: 1 counter / 64B line
    }
}

// ---- phase A: scatter (dst,src) pairs into the dst-bucket's CSR range ----
__global__ __launch_bounds__(256) void k_pairs(const int* __restrict__ src,
                                               const int* __restrict__ dst,
                                               int* __restrict__ coarse,
                                               unsigned long long* __restrict__ pairs) {
    int e = blockIdx.x * 256 + threadIdx.x;
    if (e < E) {
        int s = src[e], d = dst[e];
        int pos = atomicAdd(&coarse[(d >> 7) * 16], 1);
        pairs[pos] = ((unsigned long long)(unsigned)d << 32) | (unsigned)s;
    }
}

// ---- phase B: per-bucket scatter to col with LDS cursors ----
__global__ __launch_bounds__(256) void k_scatter(const unsigned long long* __restrict__ pairs,
                                                 const int* __restrict__ rp,
                                                 int* __restrict__ col) {
    __shared__ int lcur[128];
    int b = blockIdx.x;
    int node0 = b << 7;
    int nmax = min(128, N - node0);
    int tid = threadIdx.x;
    if (tid < nmax) lcur[tid] = rp[node0 + tid];
    int beg = rp[node0];
    int end = rp[min(node0 + 128, N)];
    __syncthreads();
    for (int e = beg + tid; e < end; e += 256) {
        unsigned long long p = pairs[e];
        int s = (int)(p & 0xffffffffu);
        int d = (int)(p >> 32);
        int pos = atomicAdd(&lcur[d - node0], 1);
        col[pos] = s;
    }
}

// ---------------- GEMM: t = ((in * a + c) * norm_s) @ W, out bf16 ----------------
// in: N x 128, W: 128 x FOUT (row-major f32), out: N x FOUT bf16
template <typename TIn, int FOUT, bool AFFINE>
__global__ __launch_bounds__(256) void k_gemm(const TIn* __restrict__ in,
                                              const float* __restrict__ W,
                                              const float* __restrict__ rowscale,
                                              const float* __restrict__ ab, // a[0..127], c[128..255]
                                              __hip_bfloat16* __restrict__ out) {
    __shared__ float Ws[64 * FOUT];
    __shared__ float Xs[32][128];
    const int tid = threadIdx.x;
    const int r0 = blockIdx.x * 32;

    for (int i = tid; i < 32 * 128; i += 256) {
        int rr = i >> 7, k = i & 127;
        int row = r0 + rr;
        float v = 0.0f;
        if (row < N) {
            v = ldf(in, row * 128 + k);
            if (AFFINE) v = v * ab[k] + ab[128 + k];
            v *= rowscale[row];
        }
        Xs[rr][k] = v;
    }

    const int wave = tid >> 6, lane = tid & 63;
    constexpr int NC = FOUT / 64;
    float acc[8][NC];
#pragma unroll
    for (int rr = 0; rr < 8; ++rr)
#pragma unroll
        for (int cc = 0; cc < NC; ++cc) acc[rr][cc] = 0.0f;

    for (int kb = 0; kb < 128; kb += 64) {
        __syncthreads();
        for (int i = tid; i < 64 * FOUT; i += 256)
            Ws[i] = W[(size_t)(kb + i / FOUT) * FOUT + (i % FOUT)];
        __syncthreads();
#pragma unroll 4
        for (int k = 0; k < 64; ++k) {
            float w0 = Ws[k * FOUT + lane];
            float w1 = (NC == 2) ? Ws[k * FOUT + 64 + lane] : 0.0f;
#pragma unroll
            for (int rr = 0; rr < 8; ++rr) {
                float xv = Xs[wave * 8 + rr][kb + k];
                acc[rr][0] += xv * w0;
                if (NC == 2) acc[rr][1] += xv * w1;
            }
        }
    }

#pragma unroll
    for (int rr = 0; rr < 8; ++rr) {
        int row = r0 + wave * 8 + rr;
        if (row < N) {
            out[(size_t)row * FOUT + lane] = __float2bfloat16(acc[rr][0]);
            if (NC == 2) out[(size_t)row * FOUT + lane + 64] = __float2bfloat16(acc[rr][1]);
        }
    }
}

// ---------------- CSR gather aggregation ----------------
__global__ __launch_bounds__(256) void k_agg128(const unsigned* __restrict__ T2, // N x 64 uints
                                                const int* __restrict__ rp,
                                                const int* __restrict__ col,
                                                float2* __restrict__ M2) {       // N x 64 float2
    int wave = threadIdx.x >> 6, lane = threadIdx.x & 63;
    int n = blockIdx.x * 4 + wave;
    if (n >= N) return;
    int beg = rp[n], end = rp[n + 1];
    float a0 = 0.0f, a1 = 0.0f;
    int e = beg;
    for (; e + 4 <= end; e += 4) {
        int s0 = col[e], s1 = col[e + 1], s2 = col[e + 2], s3 = col[e + 3];
        unsigned v0 = T2[s0 * 64 + lane];
        unsigned v1 = T2[s1 * 64 + lane];
        unsigned v2 = T2[s2 * 64 + lane];
        unsigned v3 = T2[s3 * 64 + lane];
        a0 += bflo(v0) + bflo(v1) + bflo(v2) + bflo(v3);
        a1 += bfhi(v0) + bfhi(v1) + bfhi(v2) + bfhi(v3);
    }
    for (; e < end; ++e) {
        unsigned v = T2[col[e] * 64 + lane];
        a0 += bflo(v); a1 += bfhi(v);
    }
    M2[n * 64 + lane] = make_float2(a0, a1);
}

__global__ __launch_bounds__(256) void k_agg64(const __hip_bfloat16* __restrict__ T,
                                               const int* __restrict__ rp,
                                               const int* __restrict__ col,
                                               float* __restrict__ M) {
    int wave = threadIdx.x >> 6, lane = threadIdx.x & 63;
    int n = blockIdx.x * 4 + wave;
    if (n >= N) return;
    int beg = rp[n], end = rp[n + 1];
    float a0 = 0.0f;
    int e = beg;
    for (; e + 4 <= end; e += 4) {
        int s0 = col[e], s1 = col[e + 1], s2 = col[e + 2], s3 = col[e + 3];
        float v0 = __bfloat162float(T[s0 * 64 + lane]);
        float v1 = __bfloat162float(T[s1 * 64 + lane]);
        float v2 = __bfloat162float(T[s2 * 64 + lane]);
        float v3 = __bfloat162float(T[s3 * 64 + lane]);
        a0 += v0 + v1 + v2 + v3;
    }
    for (; e < end; ++e) a0 += __bfloat162float(T[col[e] * 64 + lane]);
    M[n * 64 + lane] = a0;
}

// ---------------- post: z = m*norm_d + b; r = relu(z); H = r; BN partial sums ----------------
__global__ __launch_bounds__(256) void k_post(const float* __restrict__ M,
                                              const float* __restrict__ norm_d,
                                              const float* __restrict__ bias,
                                              __hip_bfloat16* __restrict__ H,
                                              float* __restrict__ sums) {
    int tid = threadIdx.x;
    int f = tid & 127;
    float b = bias[f];
    float s = 0.0f, sq = 0.0f;
    const int total = N * 128;
    const int stride = gridDim.x * 256;
    for (int idx = blockIdx.x * 256 + tid; idx < total; idx += stride) {
        int row = idx >> 7;
        float z = M[idx] * norm_d[row] + b;
        float r = fmaxf(z, 0.0f);
        H[idx] = __float2bfloat16(r);
        s += r; sq += r * r;
    }
    __shared__ float ls[256], lq[256];
    ls[tid] = s; lq[tid] = sq;
    __syncthreads();
    if (tid < 128) {
        atomicAdd(&sums[f], ls[tid] + ls[tid + 128]);
        atomicAdd(&sums[128 + f], lq[tid] + lq[tid + 128]);
    }
}

__global__ __launch_bounds__(128) void k_bnfin(const float* __restrict__ sums,
                                               const float* __restrict__ gamma,
                                               const float* __restrict__ beta,
                                               float* __restrict__ ab) {
    int f = threadIdx.x;
    float mu = sums[f] * (1.0f / N);
    float var = sums[128 + f] * (1.0f / N) - mu * mu;
    float a = gamma[f] * rsqrtf(var + BN_EPS);
    ab[f] = a;
    ab[128 + f] = beta[f] - mu * a;
}

// ---------------- final: z = m*norm_d + b3; log_softmax over 64 feats ----------------
__global__ __launch_bounds__(256) void k_lsm(const float* __restrict__ M,
                                             const float* __restrict__ norm_d,
                                             const float* __restrict__ b3,
                                             float* __restrict__ out) {
    int wave = threadIdx.x >> 6, lane = threadIdx.x & 63;
    int n = blockIdx.x * 4 + wave;
    if (n >= N) return;
    float z = M[n * 64 + lane] * norm_d[n] + b3[lane];
    float m = z;
    for (int off = 32; off; off >>= 1) m = fmaxf(m, __shfl_xor(m, off));
    float e = __expf(z - m);
    float ssum = e;
    for (int off = 32; off; off >>= 1) ssum += __shfl_xor(ssum, off);
    out[n * 64 + lane] = z - m - __logf(ssum);
}

extern "C" void kernel_launch(void* const* d_in, const int* in_sizes, int n_in,
                              void* d_out, int out_size, void* d_ws, size_t ws_size,
                              hipStream_t stream) {
    const float* x  = (const float*)d_in[0];
    const int* src  = (const int*)d_in[1];
    const int* dst  = (const int*)d_in[2];
    const float* W1 = (const float*)d_in[3];
    const float* b1 = (const float*)d_in[4];
    const float* W2 = (const float*)d_in[5];
    const float* b2 = (const float*)d_in[6];
    const float* W3 = (const float*)d_in[7];
    const float* b3 = (const float*)d_in[8];
    const float* g1 = (const float*)d_in[9];
    const float* be1= (const float*)d_in[10];
    const float* g2 = (const float*)d_in[11];
    const float* be2= (const float*)d_in[12];
    float* out = (float*)d_out;

    char* ws = (char*)d_ws;
    int*   deg_out = (int*)(ws + OFF_DEG_OUT);
    int*   deg_in  = (int*)(ws + OFF_DEG_IN);
    float* sums1   = (float*)(ws + OFF_SUMS1);
    float* sums2   = (float*)(ws + OFF_SUMS2);
    float* norm_s  = (float*)(ws + OFF_NORM_S);
    float* norm_d  = (float*)(ws + OFF_NORM_D);
    int*   rp      = (int*)(ws + OFF_RP);
    int*   part    = (int*)(ws + OFF_PART);
    int*   coarse  = (int*)(ws + OFF_COARSE);
    float* ab1     = (float*)(ws + OFF_AB1);
    float* ab2     = (float*)(ws + OFF_AB2);
    int*   col     = (int*)(ws + OFF_COL);
    __hip_bfloat16* H = (__hip_bfloat16*)(ws + OFF_H);
    __hip_bfloat16* T = (__hip_bfloat16*)(ws + OFF_T);
    float* M       = (float*)(ws + OFF_M);
    unsigned long long* pairs = (unsigned long long*)(ws + OFF_M);  // aliased with M

    hipMemsetAsync(ws, 0, MEMSET_BYTES, stream);

    // CSR build (by dst), two-phase bucketed scatter
    k_deg<<<(E + 255) / 256, 256, 0, stream>>>(src, dst, deg_out, deg_in);
    k_norm<<<(N + 255) / 256, 256, 0, stream>>>(deg_out, deg_in, norm_s, norm_d);
    k_part<<<NB, SCAN_B, 0, stream>>>(deg_in, part);
    k_scanpart<<<1, 128, 0, stream>>>(part, rp);
    k_apply<<<NB, SCAN_B, 0, stream>>>(deg_in, part, rp, coarse);
    k_pairs<<<(E + 255) / 256, 256, 0, stream>>>(src, dst, coarse, pairs);
    k_scatter<<<NBUCK, 256, 0, stream>>>(pairs, rp, col);

    const int gemm_grid = (N + 31) / 32;
    const int node_grid = (N + 3) / 4;

    // Layer 1
    k_gemm<float, 128, false><<<gemm_grid, 256, 0, stream>>>(x, W1, norm_s, nullptr, T);
    k_agg128<<<node_grid, 256, 0, stream>>>((const unsigned*)T, rp, col, (float2*)M);
    k_post<<<1024, 256, 0, stream>>>(M, norm_d, b1, H, sums1);
    k_bnfin<<<1, 128, 0, stream>>>(sums1, g1, be1, ab1);

    // Layer 2
    k_gemm<__hip_bfloat16, 128, true><<<gemm_grid, 256, 0, stream>>>(H, W2, norm_s, ab1, T);
    k_agg128<<<node_grid, 256, 0, stream>>>((const unsigned*)T, rp, col, (float2*)M);
    k_post<<<1024, 256, 0, stream>>>(M, norm_d, b2, H, sums2);
    k_bnfin<<<1, 128, 0, stream>>>(sums2, g2, be2, ab2);

    // Layer 3 (64 outputs) + log_softmax
    k_gemm<__hip_bfloat16, 64, true><<<gemm_grid, 256, 0, stream>>>(H, W3, norm_s, ab2, T);
    k_agg64<<<node_grid, 256, 0, stream>>>(T, rp, col, M);
    k_lsm<<<node_grid, 256, 0, stream>>>(M, norm_d, b3, out);
}